// Round 1
// baseline (545.415 us; speedup 1.0000x reference)
//
#include <hip/hip_runtime.h>

#define N_ 16
#define V_ 16384
#define D_ 128
#define E_ 65536
#define L_ 2
#define M_ (N_*V_)   // 262144 rows

typedef __attribute__((ext_vector_type(8))) short short8;
typedef __attribute__((ext_vector_type(4))) float floatx4;

__device__ inline unsigned short f2bf(float x){
  unsigned u = __builtin_bit_cast(unsigned, x);
  unsigned r = u + 0x7fffu + ((u >> 16) & 1u);
  return (unsigned short)(r >> 16);
}
__device__ inline float bf2f(unsigned short h){
  unsigned u = ((unsigned)h) << 16;
  return __builtin_bit_cast(float, u);
}
__device__ inline unsigned pack2(float a, float b){
  return (unsigned)f2bf(a) | ((unsigned)f2bf(b) << 16);
}

// ---- H (fp32) -> Xb (bf16), 8 elems/thread ----
__global__ __launch_bounds__(256) void conv_in_k(const float* __restrict__ H,
                                                 unsigned short* __restrict__ Xb){
  int i = blockIdx.x * 256 + threadIdx.x;          // handles 8 elems
  const float4* h4 = (const float4*)H;
  float4 a = h4[2*i], b = h4[2*i+1];
  uint4 o;
  o.x = pack2(a.x, a.y);
  o.y = pack2(a.z, a.w);
  o.z = pack2(b.x, b.y);
  o.w = pack2(b.z, b.w);
  ((uint4*)Xb)[i] = o;
}

// ---- weights fp32 -> bf16 in MFMA frag-major layout [l][mat][ks][ct][lane][8] ----
__global__ __launch_bounds__(256) void conv_w_k(const float* __restrict__ Wself,
                                                const float* __restrict__ Wnei,
                                                unsigned short* __restrict__ Wb){
  int f = blockIdx.x * 256 + threadIdx.x;          // 0..8191 frags
  int lane = f & 63;
  int ct   = (f >> 6) & 7;
  int ks   = (f >> 9) & 3;
  int mat  = (f >> 11) & 1;
  int l    = (f >> 12) & 1;
  int e = ct * 16 + (lane & 15);
  int d = ks * 32 + (lane >> 4) * 8;
  const float* src = (mat ? Wnei : Wself) + ((size_t)l * D_ * D_ + e * D_ + d);
  uint4 o;
  o.x = pack2(src[0], src[1]);
  o.y = pack2(src[2], src[3]);
  o.z = pack2(src[4], src[5]);
  o.w = pack2(src[6], src[7]);
  ((uint4*)Wb)[f] = o;
}

// ---- CSR build ----
__global__ __launch_bounds__(256) void hist_k(const int* __restrict__ dst, int* __restrict__ cnt){
  int e = blockIdx.x * 256 + threadIdx.x;
  atomicAdd(&cnt[dst[e]], 1);
}

__global__ __launch_bounds__(256) void scan_k(const int* __restrict__ cnt, int* __restrict__ row_ptr){
  __shared__ int part[256];
  int t = threadIdx.x;
  int base = t * 64;
  int s = 0;
  for (int i = 0; i < 64; ++i) s += cnt[base + i];
  part[t] = s;
  __syncthreads();
  for (int d = 1; d < 256; d <<= 1){
    int v = (t >= d) ? part[t - d] : 0;
    __syncthreads();
    part[t] += v;
    __syncthreads();
  }
  int off = part[t] - s;   // exclusive prefix
  for (int i = 0; i < 64; ++i){
    row_ptr[base + i] = off;
    off += cnt[base + i];
  }
  if (t == 255) row_ptr[V_] = off;
}

__global__ __launch_bounds__(256) void scatter_k(const int* __restrict__ src,
                                                 const int* __restrict__ dst,
                                                 const float* __restrict__ vals,
                                                 const int* __restrict__ row_ptr,
                                                 int* __restrict__ fill,
                                                 int* __restrict__ csr_col,
                                                 float* __restrict__ csr_val){
  int e = blockIdx.x * 256 + threadIdx.x;
  int d = dst[e];
  int pos = row_ptr[d] + atomicAdd(&fill[d], 1);
  csr_col[pos] = src[e];
  csr_val[pos] = vals[e];
}

// ---- SpMM: Xnei[n,v,:] = sum_e val[e]*Xb[n,col[e],:]  (bf16 in/out, fp32 acc) ----
__global__ __launch_bounds__(256) void spmm_k(const unsigned* __restrict__ Xb,
                                              const int* __restrict__ row_ptr,
                                              const int* __restrict__ csr_col,
                                              const float* __restrict__ csr_val,
                                              unsigned* __restrict__ Xnei){
  int v = blockIdx.x;
  int wave = threadIdx.x >> 6;
  int lane = threadIdx.x & 63;
  int r0 = row_ptr[v], r1 = row_ptr[v + 1];
  float acc[4][2] = {};
  for (int i = r0; i < r1; ++i){
    int c = csr_col[i];
    float a = csr_val[i];
#pragma unroll
    for (int t = 0; t < 4; ++t){
      int n = wave + 4 * t;
      unsigned w = Xb[((size_t)n * V_ + c) * 64 + lane];
      acc[t][0] += a * bf2f((unsigned short)(w & 0xffff));
      acc[t][1] += a * bf2f((unsigned short)(w >> 16));
    }
  }
#pragma unroll
  for (int t = 0; t < 4; ++t){
    int n = wave + 4 * t;
    Xnei[((size_t)n * V_ + v) * 64 + lane] = pack2(acc[t][0], acc[t][1]);
  }
}

// ---- GEMM: Y = Xb*Ws^T + Xnei*Wn^T (bf16 MFMA, fp32 out) + fused BN partial stats ----
__global__ __launch_bounds__(256) void gemm_k(const unsigned short* __restrict__ Xb,
                                              const unsigned short* __restrict__ Xnei,
                                              const uint4* __restrict__ Wfrag,
                                              float* __restrict__ Y,
                                              float* __restrict__ stats){
  __shared__ uint4 lds_w[4096];                     // 64 KB: [mat][ks][ct][lane]
  int tid = threadIdx.x;
  for (int i = tid; i < 4096; i += 256) lds_w[i] = Wfrag[i];
  __syncthreads();

  int wave = tid >> 6, lane = tid & 63;
  int quad = lane >> 4, l15 = lane & 15;
  int row0 = blockIdx.x * 128 + wave * 32;

  floatx4 zero = {0.f, 0.f, 0.f, 0.f};
  floatx4 acc[2][8];
#pragma unroll
  for (int rt = 0; rt < 2; ++rt)
#pragma unroll
    for (int ct = 0; ct < 8; ++ct) acc[rt][ct] = zero;

  const short8* lw = (const short8*)lds_w;
#pragma unroll
  for (int ks = 0; ks < 4; ++ks){
    short8 a_s[2], a_n[2];
#pragma unroll
    for (int rt = 0; rt < 2; ++rt){
      size_t r = (size_t)(row0 + rt * 16 + l15);
      a_s[rt] = *(const short8*)(Xb   + r * 128 + ks * 32 + quad * 8);
      a_n[rt] = *(const short8*)(Xnei + r * 128 + ks * 32 + quad * 8);
    }
#pragma unroll
    for (int ct = 0; ct < 8; ++ct){
      short8 bs = lw[((0 * 4 + ks) * 8 + ct) * 64 + lane];
      short8 bn = lw[((1 * 4 + ks) * 8 + ct) * 64 + lane];
#pragma unroll
      for (int rt = 0; rt < 2; ++rt){
        acc[rt][ct] = __builtin_amdgcn_mfma_f32_16x16x32_bf16(a_s[rt], bs, acc[rt][ct], 0, 0, 0);
        acc[rt][ct] = __builtin_amdgcn_mfma_f32_16x16x32_bf16(a_n[rt], bn, acc[rt][ct], 0, 0, 0);
      }
    }
  }

  // epilogue: store Y (C layout: col=lane&15, row=quad*4+reg) + fused column stats
  float* sum_base = stats;            // [64][128]
  float* sq_base  = stats + 64 * 128; // [64][128]
  int slot = blockIdx.x & 63;
#pragma unroll
  for (int rt = 0; rt < 2; ++rt){
    int rowq = row0 + rt * 16 + quad * 4;
#pragma unroll
    for (int ct = 0; ct < 8; ++ct){
      int col = ct * 16 + l15;
      float s = 0.f, q = 0.f;
#pragma unroll
      for (int rg = 0; rg < 4; ++rg){
        float yv = acc[rt][ct][rg];
        Y[(size_t)(rowq + rg) * 128 + col] = yv;
        s += yv; q += yv * yv;
      }
      s += __shfl_xor(s, 16); s += __shfl_xor(s, 32);
      q += __shfl_xor(q, 16); q += __shfl_xor(q, 32);
      if (lane < 16)      atomicAdd(&sum_base[slot * 128 + ct * 16 + lane], s);
      else if (lane < 32) atomicAdd(&sq_base [slot * 128 + ct * 16 + (lane & 15)], q);
    }
  }
}

// ---- reduce stats -> scale/shift ----
__global__ __launch_bounds__(128) void finalize_k(const float* __restrict__ stats,
                                                  const float* __restrict__ gamma,
                                                  const float* __restrict__ beta,
                                                  float* __restrict__ scsh){
  int d = threadIdx.x;
  float s = 0.f, q = 0.f;
  for (int k = 0; k < 64; ++k){
    s += stats[k * 128 + d];
    q += stats[64 * 128 + k * 128 + d];
  }
  float inv = 1.0f / (float)M_;
  float mean = s * inv;
  float var  = q * inv - mean * mean;
  float rstd = rsqrtf(var + 1e-5f);
  float scale = gamma[d] * rstd;
  scsh[d]       = scale;
  scsh[128 + d] = beta[d] - mean * scale;
}

// ---- BN apply + ReLU; OUT_BF16=1 -> bf16 (next layer X), else fp32 in place ----
template<int OUT_BF16>
__global__ __launch_bounds__(256) void bn_relu_k(const float* __restrict__ Y,
                                                 const float* __restrict__ scsh,
                                                 float* __restrict__ outf,
                                                 unsigned* __restrict__ outb){
  int i = blockIdx.x * 256 + threadIdx.x;          // 4 elems
  int c = (i * 4) & 127;
  float4 y  = ((const float4*)Y)[i];
  float4 sc = *(const float4*)(scsh + c);
  float4 sh = *(const float4*)(scsh + 128 + c);
  float o0 = fmaxf(0.f, y.x * sc.x + sh.x);
  float o1 = fmaxf(0.f, y.y * sc.y + sh.y);
  float o2 = fmaxf(0.f, y.z * sc.z + sh.z);
  float o3 = fmaxf(0.f, y.w * sc.w + sh.w);
  if (OUT_BF16){
    uint2 o; o.x = pack2(o0, o1); o.y = pack2(o2, o3);
    ((uint2*)outb)[i] = o;
  } else {
    float4 o; o.x = o0; o.y = o1; o.z = o2; o.w = o3;
    ((float4*)outf)[i] = o;
  }
}

static inline size_t align_up(size_t x, size_t a){ return (x + a - 1) & ~(a - 1); }

extern "C" void kernel_launch(void* const* d_in, const int* in_sizes, int n_in,
                              void* d_out, int out_size, void* d_ws, size_t ws_size,
                              hipStream_t stream){
  const float* H     = (const float*)d_in[0];
  const int*   esrc  = (const int*)  d_in[1];
  const int*   edst  = (const int*)  d_in[2];
  const float* avals = (const float*)d_in[3];
  const float* Wself = (const float*)d_in[4];
  const float* Wnei  = (const float*)d_in[5];
  const float* gamma = (const float*)d_in[6];
  const float* beta  = (const float*)d_in[7];
  float* Y = (float*)d_out;   // 262144 x 128 fp32, reused as Y scratch per layer

  char* ws = (char*)d_ws;
  size_t off = 0;
  unsigned short* Xb   = (unsigned short*)(ws + off); off += align_up((size_t)M_ * D_ * 2, 256);
  unsigned short* Xnei = (unsigned short*)(ws + off); off += align_up((size_t)M_ * D_ * 2, 256);
  unsigned short* Wb   = (unsigned short*)(ws + off); off += align_up((size_t)L_ * 2 * D_ * D_ * 2, 256);
  int*   row_ptr = (int*)  (ws + off); off += align_up((size_t)(V_ + 1) * 4, 256);
  int*   cnt     = (int*)  (ws + off); off += align_up((size_t)V_ * 4, 256);
  int*   csr_col = (int*)  (ws + off); off += align_up((size_t)E_ * 4, 256);
  float* csr_val = (float*)(ws + off); off += align_up((size_t)E_ * 4, 256);
  float* stats   = (float*)(ws + off); off += align_up((size_t)64 * 128 * 2 * 4, 256);
  float* scsh    = (float*)(ws + off); off += align_up((size_t)2 * 128 * 4, 256);
  (void)ws_size; (void)in_sizes; (void)n_in; (void)out_size;

  // input conversions
  conv_in_k<<<M_ * D_ / 8 / 256, 256, 0, stream>>>(H, Xb);
  conv_w_k<<<8192 / 256, 256, 0, stream>>>(Wself, Wnei, Wb);

  // CSR build (cheap, every call)
  hipMemsetAsync(cnt, 0, (size_t)V_ * 4, stream);
  hist_k<<<E_ / 256, 256, 0, stream>>>(edst, cnt);
  scan_k<<<1, 256, 0, stream>>>(cnt, row_ptr);
  hipMemsetAsync(cnt, 0, (size_t)V_ * 4, stream);
  scatter_k<<<E_ / 256, 256, 0, stream>>>(esrc, edst, avals, row_ptr, cnt, csr_col, csr_val);

  for (int l = 0; l < L_; ++l){
    spmm_k<<<V_, 256, 0, stream>>>((const unsigned*)Xb, row_ptr, csr_col, csr_val,
                                   (unsigned*)Xnei);
    hipMemsetAsync(stats, 0, (size_t)64 * 128 * 2 * 4, stream);
    gemm_k<<<M_ / 128, 256, 0, stream>>>(Xb, Xnei, (const uint4*)Wb + (size_t)l * 4096,
                                         Y, stats);
    finalize_k<<<1, 128, 0, stream>>>(stats, gamma + l * 128, beta + l * 128, scsh);
    if (l == 0)
      bn_relu_k<1><<<M_ * D_ / 4 / 256, 256, 0, stream>>>(Y, scsh, nullptr, (unsigned*)Xb);
    else
      bn_relu_k<0><<<M_ * D_ / 4 / 256, 256, 0, stream>>>(Y, scsh, Y, nullptr);
  }
}

// Round 2
// 495.472 us; speedup vs baseline: 1.1008x; 1.1008x over previous
//
#include <hip/hip_runtime.h>

#define N_ 16
#define V_ 16384
#define D_ 128
#define E_ 65536
#define L_ 2
#define M_ (N_*V_)   // 262144 rows

typedef __attribute__((ext_vector_type(8))) short short8;
typedef __attribute__((ext_vector_type(4))) float floatx4;

__device__ inline unsigned short f2bf(float x){
  unsigned u = __builtin_bit_cast(unsigned, x);
  unsigned r = u + 0x7fffu + ((u >> 16) & 1u);
  return (unsigned short)(r >> 16);
}
__device__ inline float bf2f(unsigned short h){
  unsigned u = ((unsigned)h) << 16;
  return __builtin_bit_cast(float, u);
}
__device__ inline unsigned pack2(float a, float b){
  return (unsigned)f2bf(a) | ((unsigned)f2bf(b) << 16);
}

// ---- H (fp32) -> Xb (bf16), 8 elems/thread ----
__global__ __launch_bounds__(256) void conv_in_k(const float* __restrict__ H,
                                                 unsigned short* __restrict__ Xb){
  int i = blockIdx.x * 256 + threadIdx.x;
  const float4* h4 = (const float4*)H;
  float4 a = h4[2*i], b = h4[2*i+1];
  uint4 o;
  o.x = pack2(a.x, a.y);
  o.y = pack2(a.z, a.w);
  o.z = pack2(b.x, b.y);
  o.w = pack2(b.z, b.w);
  ((uint4*)Xb)[i] = o;
}

// ---- weights fp32 -> bf16 in MFMA frag-major layout [l][mat][ks][ct][lane][8] ----
__global__ __launch_bounds__(256) void conv_w_k(const float* __restrict__ Wself,
                                                const float* __restrict__ Wnei,
                                                unsigned short* __restrict__ Wb){
  int f = blockIdx.x * 256 + threadIdx.x;          // 0..8191 frags
  int lane = f & 63;
  int ct   = (f >> 6) & 7;
  int ks   = (f >> 9) & 3;
  int mat  = (f >> 11) & 1;
  int l    = (f >> 12) & 1;
  int e = ct * 16 + (lane & 15);
  int d = ks * 32 + (lane >> 4) * 8;
  const float* src = (mat ? Wnei : Wself) + ((size_t)l * D_ * D_ + e * D_ + d);
  uint4 o;
  o.x = pack2(src[0], src[1]);
  o.y = pack2(src[2], src[3]);
  o.z = pack2(src[4], src[5]);
  o.w = pack2(src[6], src[7]);
  ((uint4*)Wb)[f] = o;
}

// ---- CSR build ----
__global__ __launch_bounds__(256) void hist_k(const int* __restrict__ dst, int* __restrict__ cnt){
  int e = blockIdx.x * 256 + threadIdx.x;
  atomicAdd(&cnt[dst[e]], 1);
}

__global__ __launch_bounds__(256) void scan_k(const int* __restrict__ cnt, int* __restrict__ row_ptr){
  __shared__ int part[256];
  int t = threadIdx.x;
  int base = t * 64;
  int s = 0;
  for (int i = 0; i < 64; ++i) s += cnt[base + i];
  part[t] = s;
  __syncthreads();
  for (int d = 1; d < 256; d <<= 1){
    int v = (t >= d) ? part[t - d] : 0;
    __syncthreads();
    part[t] += v;
    __syncthreads();
  }
  int off = part[t] - s;   // exclusive prefix
  for (int i = 0; i < 64; ++i){
    row_ptr[base + i] = off;
    off += cnt[base + i];
  }
  if (t == 255) row_ptr[V_] = off;
}

__global__ __launch_bounds__(256) void scatter_k(const int* __restrict__ src,
                                                 const int* __restrict__ dst,
                                                 const float* __restrict__ vals,
                                                 const int* __restrict__ row_ptr,
                                                 int* __restrict__ fill,
                                                 int* __restrict__ csr_col,
                                                 float* __restrict__ csr_val){
  int e = blockIdx.x * 256 + threadIdx.x;
  int d = dst[e];
  int pos = row_ptr[d] + atomicAdd(&fill[d], 1);
  csr_col[pos] = src[e];
  csr_val[pos] = vals[e];
}

// ---- SpMM: Xnei[n,v,:] = sum val*X[n,col,:] ; NORM applies relu(x*sc+sh) to gathered X ----
template<int NORM>
__global__ __launch_bounds__(256) void spmm_k(const unsigned* __restrict__ X,
                                              const int* __restrict__ row_ptr,
                                              const int* __restrict__ csr_col,
                                              const float* __restrict__ csr_val,
                                              const float* __restrict__ scsh,
                                              unsigned* __restrict__ Xnei){
  int v = blockIdx.x;
  int tid = threadIdx.x;
  int wave = tid >> 6, lane = tid & 63;
  int l31 = lane & 31, nh = lane >> 5;
  float4 sc = {0.f,0.f,0.f,0.f}, sh = {0.f,0.f,0.f,0.f};
  if (NORM){
    sc = ((const float4*)scsh)[l31];
    sh = ((const float4*)(scsh + 128))[l31];
  }
  int r0 = row_ptr[v], r1 = row_ptr[v + 1];
  float acc[2][4] = {{0.f,0.f,0.f,0.f},{0.f,0.f,0.f,0.f}};
  for (int i = r0; i < r1; ++i){
    int c = csr_col[i];
    float a = csr_val[i];
#pragma unroll
    for (int p = 0; p < 2; ++p){
      int n = p * 8 + wave * 2 + nh;
      uint2 w = *((const uint2*)(X + ((size_t)n * V_ + c) * 64) + l31);
      float x0 = bf2f((unsigned short)(w.x & 0xffff));
      float x1 = bf2f((unsigned short)(w.x >> 16));
      float x2 = bf2f((unsigned short)(w.y & 0xffff));
      float x3 = bf2f((unsigned short)(w.y >> 16));
      if (NORM){
        x0 = fmaxf(0.f, x0 * sc.x + sh.x);
        x1 = fmaxf(0.f, x1 * sc.y + sh.y);
        x2 = fmaxf(0.f, x2 * sc.z + sh.z);
        x3 = fmaxf(0.f, x3 * sc.w + sh.w);
      }
      acc[p][0] += a * x0; acc[p][1] += a * x1;
      acc[p][2] += a * x2; acc[p][3] += a * x3;
    }
  }
#pragma unroll
  for (int p = 0; p < 2; ++p){
    int n = p * 8 + wave * 2 + nh;
    uint2 o;
    o.x = pack2(acc[p][0], acc[p][1]);
    o.y = pack2(acc[p][2], acc[p][3]);
    *((uint2*)(Xnei + ((size_t)n * V_ + v) * 64) + l31) = o;
  }
}

// ---- GEMM: Y = Xs*Ws^T + Xn*Wn^T (bf16 MFMA) -> Y bf16 + fused BN partial stats.
//      NORM: Xs holds raw prev-layer Y; apply relu(x*sc+sh) to A-self frags. ----
template<int NORM>
__global__ __launch_bounds__(256, 2) void gemm_k(const unsigned short* __restrict__ Xs,
                                                 const unsigned short* __restrict__ Xn,
                                                 const uint4* __restrict__ Wfrag,
                                                 const float* __restrict__ scsh,
                                                 unsigned short* __restrict__ Yb,
                                                 float* __restrict__ stats){
  __shared__ uint4 lds_w[4096];                     // 64 KB: [mat][ks][ct][lane]
  __shared__ float lds_s[256];
  int tid = threadIdx.x;
  for (int i = tid; i < 4096; i += 256) lds_w[i] = Wfrag[i];
  if (NORM) lds_s[tid] = scsh[tid];
  __syncthreads();

  int wave = tid >> 6, lane = tid & 63;
  int quad = lane >> 4, l15 = lane & 15;
  int row0 = blockIdx.x * 128 + wave * 32;

  floatx4 zero = {0.f, 0.f, 0.f, 0.f};
  floatx4 acc[2][8];
#pragma unroll
  for (int rt = 0; rt < 2; ++rt)
#pragma unroll
    for (int ct = 0; ct < 8; ++ct) acc[rt][ct] = zero;

  const short8* lw = (const short8*)lds_w;
#pragma unroll
  for (int ks = 0; ks < 4; ++ks){
    float scv[8], shv[8];
    if (NORM){
      int cb = ks * 32 + quad * 8;
#pragma unroll
      for (int j = 0; j < 8; ++j){
        scv[j] = lds_s[cb + j];
        shv[j] = lds_s[128 + cb + j];
      }
    }
    short8 a_s[2], a_n[2];
#pragma unroll
    for (int rt = 0; rt < 2; ++rt){
      size_t r = (size_t)(row0 + rt * 16 + l15);
      short8 raw = *(const short8*)(Xs + r * 128 + ks * 32 + quad * 8);
      if (NORM){
        short8 t;
#pragma unroll
        for (int j = 0; j < 8; ++j){
          float x = bf2f((unsigned short)raw[j]);
          x = fmaxf(0.f, x * scv[j] + shv[j]);
          t[j] = (short)f2bf(x);
        }
        a_s[rt] = t;
      } else {
        a_s[rt] = raw;
      }
      a_n[rt] = *(const short8*)(Xn + r * 128 + ks * 32 + quad * 8);
    }
#pragma unroll
    for (int ct = 0; ct < 8; ++ct){
      short8 bs = lw[((0 * 4 + ks) * 8 + ct) * 64 + lane];
      short8 bn = lw[((1 * 4 + ks) * 8 + ct) * 64 + lane];
#pragma unroll
      for (int rt = 0; rt < 2; ++rt){
        acc[rt][ct] = __builtin_amdgcn_mfma_f32_16x16x32_bf16(a_s[rt], bs, acc[rt][ct], 0, 0, 0);
        acc[rt][ct] = __builtin_amdgcn_mfma_f32_16x16x32_bf16(a_n[rt], bn, acc[rt][ct], 0, 0, 0);
      }
    }
  }

  // epilogue: bf16 Y store (C layout: col=lane&15, row=quad*4+reg) + fused column stats
  float* sum_base = stats;            // [64][128]
  float* sq_base  = stats + 64 * 128; // [64][128]
  int slot = blockIdx.x & 63;
#pragma unroll
  for (int rt = 0; rt < 2; ++rt){
    int rowq = row0 + rt * 16 + quad * 4;
#pragma unroll
    for (int ct = 0; ct < 8; ++ct){
      int col = ct * 16 + l15;
      float s = 0.f, q = 0.f;
#pragma unroll
      for (int rg = 0; rg < 4; ++rg){
        float yv = acc[rt][ct][rg];
        Yb[(size_t)(rowq + rg) * 128 + col] = f2bf(yv);
        s += yv; q += yv * yv;
      }
      s += __shfl_xor(s, 16); s += __shfl_xor(s, 32);
      q += __shfl_xor(q, 16); q += __shfl_xor(q, 32);
      if (lane < 16)      atomicAdd(&sum_base[slot * 128 + ct * 16 + lane], s);
      else if (lane < 32) atomicAdd(&sq_base [slot * 128 + ct * 16 + (lane & 15)], q);
    }
  }
}

// ---- reduce stats -> scale/shift ----
__global__ __launch_bounds__(128) void finalize_k(const float* __restrict__ stats,
                                                  const float* __restrict__ gamma,
                                                  const float* __restrict__ beta,
                                                  float* __restrict__ scsh){
  int d = threadIdx.x;
  float s = 0.f, q = 0.f;
  for (int k = 0; k < 64; ++k){
    s += stats[k * 128 + d];
    q += stats[64 * 128 + k * 128 + d];
  }
  float inv = 1.0f / (float)M_;
  float mean = s * inv;
  float var  = q * inv - mean * mean;
  float rstd = rsqrtf(var + 1e-5f);
  float scale = gamma[d] * rstd;
  scsh[d]       = scale;
  scsh[128 + d] = beta[d] - mean * scale;
}

// ---- final BN apply + ReLU: Y bf16 -> fp32 d_out ----
__global__ __launch_bounds__(256) void bn_out_k(const uint4* __restrict__ Y,
                                                const float* __restrict__ scsh,
                                                float4* __restrict__ out){
  int i = blockIdx.x * 256 + threadIdx.x;          // 8 elems
  int c = (i * 8) & 127;
  uint4 y = Y[i];
  float4 sc0 = *(const float4*)(scsh + c);
  float4 sc1 = *(const float4*)(scsh + c + 4);
  float4 sh0 = *(const float4*)(scsh + 128 + c);
  float4 sh1 = *(const float4*)(scsh + 132 + c);
  float4 o0, o1;
  o0.x = fmaxf(0.f, bf2f((unsigned short)(y.x & 0xffff)) * sc0.x + sh0.x);
  o0.y = fmaxf(0.f, bf2f((unsigned short)(y.x >> 16))    * sc0.y + sh0.y);
  o0.z = fmaxf(0.f, bf2f((unsigned short)(y.y & 0xffff)) * sc0.z + sh0.z);
  o0.w = fmaxf(0.f, bf2f((unsigned short)(y.y >> 16))    * sc0.w + sh0.w);
  o1.x = fmaxf(0.f, bf2f((unsigned short)(y.z & 0xffff)) * sc1.x + sh1.x);
  o1.y = fmaxf(0.f, bf2f((unsigned short)(y.z >> 16))    * sc1.y + sh1.y);
  o1.z = fmaxf(0.f, bf2f((unsigned short)(y.w & 0xffff)) * sc1.z + sh1.z);
  o1.w = fmaxf(0.f, bf2f((unsigned short)(y.w >> 16))    * sc1.w + sh1.w);
  out[2 * i]     = o0;
  out[2 * i + 1] = o1;
}

static inline size_t align_up(size_t x, size_t a){ return (x + a - 1) & ~(a - 1); }

extern "C" void kernel_launch(void* const* d_in, const int* in_sizes, int n_in,
                              void* d_out, int out_size, void* d_ws, size_t ws_size,
                              hipStream_t stream){
  const float* H     = (const float*)d_in[0];
  const int*   esrc  = (const int*)  d_in[1];
  const int*   edst  = (const int*)  d_in[2];
  const float* avals = (const float*)d_in[3];
  const float* Wself = (const float*)d_in[4];
  const float* Wnei  = (const float*)d_in[5];
  const float* gamma = (const float*)d_in[6];
  const float* beta  = (const float*)d_in[7];

  char* ws = (char*)d_ws;
  size_t off = 0;
  unsigned short* Xb   = (unsigned short*)(ws + off); off += align_up((size_t)M_ * D_ * 2, 256);
  unsigned short* Xnei = (unsigned short*)(ws + off); off += align_up((size_t)M_ * D_ * 2, 256);
  unsigned short* Y0   = (unsigned short*)(ws + off); off += align_up((size_t)M_ * D_ * 2, 256);
  unsigned short* Wb   = (unsigned short*)(ws + off); off += align_up((size_t)L_ * 2 * D_ * D_ * 2, 256);
  int*   row_ptr = (int*)  (ws + off); off += align_up((size_t)(V_ + 1) * 4, 256);
  int*   csr_col = (int*)  (ws + off); off += align_up((size_t)E_ * 4, 256);
  float* csr_val = (float*)(ws + off); off += align_up((size_t)E_ * 4, 256);
  float* scsh0   = (float*)(ws + off); off += align_up((size_t)2 * 128 * 4, 256);
  float* scsh1   = (float*)(ws + off); off += align_up((size_t)2 * 128 * 4, 256);
  // contiguous zeroed region: cnt | fill | stats0 | stats1
  char* zbase = ws + off;
  int*   cnt    = (int*)  (ws + off); off += (size_t)V_ * 4;
  int*   fill   = (int*)  (ws + off); off += (size_t)V_ * 4;
  float* stats0 = (float*)(ws + off); off += (size_t)64 * 128 * 2 * 4;
  float* stats1 = (float*)(ws + off); off += (size_t)64 * 128 * 2 * 4;
  size_t zbytes = (size_t)(ws + off - zbase);
  unsigned short* Y1 = Xb;   // Xb is dead after gemm<0> reads it
  (void)ws_size; (void)in_sizes; (void)n_in; (void)out_size;

  conv_in_k<<<M_ * D_ / 8 / 256, 256, 0, stream>>>(H, Xb);
  conv_w_k<<<8192 / 256, 256, 0, stream>>>(Wself, Wnei, Wb);
  hipMemsetAsync(zbase, 0, zbytes, stream);
  hist_k<<<E_ / 256, 256, 0, stream>>>(edst, cnt);
  scan_k<<<1, 256, 0, stream>>>(cnt, row_ptr);
  scatter_k<<<E_ / 256, 256, 0, stream>>>(esrc, edst, avals, row_ptr, fill, csr_col, csr_val);

  // ---- layer 0 ----
  spmm_k<0><<<V_, 256, 0, stream>>>((const unsigned*)Xb, row_ptr, csr_col, csr_val,
                                    nullptr, (unsigned*)Xnei);
  gemm_k<0><<<M_ / 128, 256, 0, stream>>>(Xb, Xnei, (const uint4*)Wb, nullptr, Y0, stats0);
  finalize_k<<<1, 128, 0, stream>>>(stats0, gamma, beta, scsh0);

  // ---- layer 1 (BN+ReLU of layer 0 fused into consumers) ----
  spmm_k<1><<<V_, 256, 0, stream>>>((const unsigned*)Y0, row_ptr, csr_col, csr_val,
                                    scsh0, (unsigned*)Xnei);
  gemm_k<1><<<M_ / 128, 256, 0, stream>>>(Y0, Xnei, (const uint4*)Wb + 4096, scsh0, Y1, stats1);
  finalize_k<<<1, 128, 0, stream>>>(stats1, gamma + 128, beta + 128, scsh1);
  bn_out_k<<<M_ * D_ / 8 / 256, 256, 0, stream>>>((const uint4*)Y1, scsh1, (float4*)d_out);
}